// Round 1
// baseline (4794.987 us; speedup 1.0000x reference)
//
#include <hip/hip_runtime.h>
#include <math.h>

namespace {

constexpr int D    = 49;   // dim == num_patches
constexpr int H    = 8;
constexpr int L    = 4;
constexpr int ST   = 52;   // LDS row stride (floats), multiple of 4 for float4
constexpr int HID  = 25;
constexpr int NCLS = 10;

// acc[e] += sum_k lrow[k] * wp[k*D + e]   (wp is wave-uniform -> s_load stream)
__device__ __forceinline__ void mm_row_acc(const float* lrow,
                                           const float* __restrict__ wp,
                                           float* acc) {
  #pragma unroll 1
  for (int k = 0; k < D; ++k) {
    const float a = lrow[k];
    const float* w = wp + k * D;
    #pragma unroll
    for (int e = 0; e < D; ++e) acc[e] = fmaf(a, w[e], acc[e]);
  }
}

__global__ void __launch_bounds__(64)
encoder_kernel(const float* __restrict__ emb, const int* __restrict__ labels,
               const float* __restrict__ Wq, const float* __restrict__ bq,
               const float* __restrict__ Wk, const float* __restrict__ bk,
               const float* __restrict__ Wv, const float* __restrict__ bv,
               const float* __restrict__ Wh, const float* __restrict__ bh,
               const float* __restrict__ Wout,
               const float* __restrict__ W1, const float* __restrict__ b1,
               const float* __restrict__ W2, const float* __restrict__ b2,
               const float* __restrict__ Wc1, const float* __restrict__ bc1,
               const float* __restrict__ Wc2, const float* __restrict__ bc2,
               float* __restrict__ ws_loss, float* __restrict__ ws_corr) {
  __shared__ float X[D * ST];   // activations x (rows 0..48)
  __shared__ float KB[D * ST];  // K rows; later ho staging / od staging / scratch
  __shared__ float VB[D * ST];  // V rows; later ctx staging / t staging / scratch

  const int b    = blockIdx.x;
  const int lane = threadIdx.x;                  // block == 1 wave (64 lanes)
  const int ii   = lane < D ? lane : (D - 1);    // lanes 49..63 mirror row 48

  // ---- load x = embedding[b] ----
  for (int idx = lane; idx < D * D; idx += 64)
    X[(idx / D) * ST + (idx % D)] = emb[(size_t)b * (D * D) + idx];
  __syncthreads();

  const float invSCALE = 1.0f / (7.0f + 1e-6f);  // 1/(sqrt(49)+1e-6), fp32

  #pragma unroll 1
  for (int l = 0; l < L; ++l) {
    float od[D];                                  // xn row: sum_h ho @ Wout
    #pragma unroll
    for (int e = 0; e < D; ++e) od[e] = 0.0f;

    #pragma unroll 1
    for (int h = 0; h < H; ++h) {
      const int lh = l * H + h;
      const float* wqp = Wq + (size_t)lh * D * D;
      const float* wkp = Wk + (size_t)lh * D * D;
      const float* wvp = Wv + (size_t)lh * D * D;
      const float* whp = Wh + (size_t)lh * D * D;
      const float* wop = Wout + (size_t)lh * D * D;

      // ---- K row -> KB ----
      {
        float kr[D];
        const float* bp = bk + lh * D;
        #pragma unroll
        for (int e = 0; e < D; ++e) kr[e] = bp[e];
        mm_row_acc(&X[ii * ST], wkp, kr);
        #pragma unroll
        for (int e4 = 0; e4 < 12; ++e4)
          reinterpret_cast<float4*>(&KB[ii * ST])[e4] =
              make_float4(kr[4 * e4], kr[4 * e4 + 1], kr[4 * e4 + 2], kr[4 * e4 + 3]);
        KB[ii * ST + 48] = kr[48];
      }
      // ---- V row -> VB ----
      {
        float vr[D];
        const float* bp = bv + lh * D;
        #pragma unroll
        for (int e = 0; e < D; ++e) vr[e] = bp[e];
        mm_row_acc(&X[ii * ST], wvp, vr);
        #pragma unroll
        for (int e4 = 0; e4 < 12; ++e4)
          reinterpret_cast<float4*>(&VB[ii * ST])[e4] =
              make_float4(vr[4 * e4], vr[4 * e4 + 1], vr[4 * e4 + 2], vr[4 * e4 + 3]);
        VB[ii * ST + 48] = vr[48];
      }
      // ---- Q row in registers ----
      float q[D];
      {
        const float* bp = bq + lh * D;
        #pragma unroll
        for (int e = 0; e < D; ++e) q[e] = bp[e];
        mm_row_acc(&X[ii * ST], wqp, q);
      }
      __syncthreads();  // K/V visible before cross-lane reads

      // ---- fused scores + online softmax (defer-max) + ctx ----
      float ctx[D];
      #pragma unroll
      for (int e = 0; e < D; ++e) ctx[e] = 0.0f;
      float m = -INFINITY, den = 0.0f;

      #pragma unroll 1
      for (int j = 0; j < D; ++j) {
        const float* kr = &KB[j * ST];       // uniform addr -> LDS broadcast
        float s = q[48] * kr[48];
        #pragma unroll
        for (int e4 = 0; e4 < 12; ++e4) {
          const float4 kv = reinterpret_cast<const float4*>(kr)[e4];
          s = fmaf(q[4 * e4 + 0], kv.x, s);
          s = fmaf(q[4 * e4 + 1], kv.y, s);
          s = fmaf(q[4 * e4 + 2], kv.z, s);
          s = fmaf(q[4 * e4 + 3], kv.w, s);
        }
        s *= invSCALE;
        s = fminf(fmaxf(s, -30.0f), 30.0f);
        if (s > m + 8.0f) {                  // defer-max rescale (THR=8)
          const float r = __expf(m - s);     // expf(-inf)=0 handles first iter
          den *= r;
          #pragma unroll
          for (int e = 0; e < D; ++e) ctx[e] *= r;
          m = s;
        }
        const float p = __expf(s - m);
        den += p;
        const float* vr = &VB[j * ST];
        #pragma unroll
        for (int e4 = 0; e4 < 12; ++e4) {
          const float4 vv = reinterpret_cast<const float4*>(vr)[e4];
          ctx[4 * e4 + 0] = fmaf(p, vv.x, ctx[4 * e4 + 0]);
          ctx[4 * e4 + 1] = fmaf(p, vv.y, ctx[4 * e4 + 1]);
          ctx[4 * e4 + 2] = fmaf(p, vv.z, ctx[4 * e4 + 2]);
          ctx[4 * e4 + 3] = fmaf(p, vv.w, ctx[4 * e4 + 3]);
        }
        ctx[48] = fmaf(p, vr[48], ctx[48]);
      }
      const float invden = 1.0f / den;
      #pragma unroll
      for (int e = 0; e < D; ++e) ctx[e] *= invden;
      __syncthreads();  // all lanes done reading KB/VB before overwrite

      // ---- ctx -> VB (stream source for ho) ----
      #pragma unroll
      for (int e4 = 0; e4 < 12; ++e4)
        reinterpret_cast<float4*>(&VB[ii * ST])[e4] =
            make_float4(ctx[4 * e4], ctx[4 * e4 + 1], ctx[4 * e4 + 2], ctx[4 * e4 + 3]);
      VB[ii * ST + 48] = ctx[48];

      // ---- ho = ctx @ Wh + bh ----
      float ho[D];
      {
        const float* bp = bh + lh * D;
        #pragma unroll
        for (int o = 0; o < D; ++o) ho[o] = bp[o];
        mm_row_acc(&VB[ii * ST], whp, ho);
      }
      // ---- ho -> KB, then od += ho @ Wout ----
      #pragma unroll
      for (int e4 = 0; e4 < 12; ++e4)
        reinterpret_cast<float4*>(&KB[ii * ST])[e4] =
            make_float4(ho[4 * e4], ho[4 * e4 + 1], ho[4 * e4 + 2], ho[4 * e4 + 3]);
      KB[ii * ST + 48] = ho[48];
      mm_row_acc(&KB[ii * ST], wop, od);
    }  // heads

    // ---- MLP between blocks (no activation) ----
    // od -> KB
    #pragma unroll
    for (int e4 = 0; e4 < 12; ++e4)
      reinterpret_cast<float4*>(&KB[ii * ST])[e4] =
          make_float4(od[4 * e4], od[4 * e4 + 1], od[4 * e4 + 2], od[4 * e4 + 3]);
    KB[ii * ST + 48] = od[48];

    float t[D];
    {
      const float* bp = b1 + l * D;
      #pragma unroll
      for (int jj = 0; jj < D; ++jj) t[jj] = bp[jj];
      mm_row_acc(&KB[ii * ST], W1 + (size_t)l * D * D, t);
    }
    #pragma unroll
    for (int e4 = 0; e4 < 12; ++e4)
      reinterpret_cast<float4*>(&VB[ii * ST])[e4] =
          make_float4(t[4 * e4], t[4 * e4 + 1], t[4 * e4 + 2], t[4 * e4 + 3]);
    VB[ii * ST + 48] = t[48];

    float x2[D];
    {
      const float* bp = b2 + l * D;
      #pragma unroll
      for (int jj = 0; jj < D; ++jj) x2[jj] = bp[jj];
      mm_row_acc(&VB[ii * ST], W2 + (size_t)l * D * D, x2);
    }
    #pragma unroll
    for (int e4 = 0; e4 < 12; ++e4)
      reinterpret_cast<float4*>(&X[ii * ST])[e4] =
          make_float4(x2[4 * e4], x2[4 * e4 + 1], x2[4 * e4 + 2], x2[4 * e4 + 3]);
    X[ii * ST + 48] = x2[48];
    __syncthreads();
  }  // layers

  // ---- classifier head ----
  if (lane < D) {
    float s = 0.0f;
    #pragma unroll 1
    for (int r = 0; r < D; ++r) s += X[r * ST + lane];
    KB[lane] = s / 49.0f;  // pooled
  }
  __syncthreads();
  if (lane < HID) {
    float acc = bc1[lane];
    #pragma unroll 1
    for (int d = 0; d < D; ++d) acc = fmaf(KB[d], Wc1[d * HID + lane], acc);
    VB[lane] = acc;
  }
  __syncthreads();
  if (lane < NCLS) {
    float acc = bc2[lane];
    #pragma unroll 1
    for (int j = 0; j < HID; ++j) acc = fmaf(VB[j], Wc2[j * NCLS + lane], acc);
    KB[64 + lane] = acc;  // logits
  }
  __syncthreads();
  if (lane == 0) {
    float mx = KB[64];
    int am = 0;
    #pragma unroll 1
    for (int c = 1; c < NCLS; ++c) {
      const float v = KB[64 + c];
      if (v > mx) { mx = v; am = c; }  // strict '>' == first max (jnp.argmax)
    }
    float se = 0.0f;
    #pragma unroll 1
    for (int c = 0; c < NCLS; ++c) se += expf(KB[64 + c] - mx);
    const float lse = mx + logf(se);
    const int lbl = labels[b];
    ws_loss[b] = lse - KB[64 + lbl];
    ws_corr[b] = (am == lbl) ? 1.0f : 0.0f;
  }
}

__global__ void __launch_bounds__(256)
reduce_kernel(const float* __restrict__ wsl, const float* __restrict__ wsc,
              float* __restrict__ out, int n) {
  __shared__ float sl[256];
  __shared__ float sc[256];
  const int t = threadIdx.x;
  float a = 0.0f, c = 0.0f;
  for (int idx = t; idx < n; idx += 256) { a += wsl[idx]; c += wsc[idx]; }
  sl[t] = a; sc[t] = c;
  __syncthreads();
  for (int s = 128; s > 0; s >>= 1) {
    if (t < s) { sl[t] += sl[t + s]; sc[t] += sc[t + s]; }
    __syncthreads();
  }
  if (t == 0) {
    out[0] = sl[0] / (float)n;  // loss
    out[1] = sc[0] / (float)n;  // accuracy
  }
}

}  // namespace

extern "C" void kernel_launch(void* const* d_in, const int* in_sizes, int n_in,
                              void* d_out, int out_size, void* d_ws, size_t ws_size,
                              hipStream_t stream) {
  const float* emb    = (const float*)d_in[0];
  const int*   labels = (const int*)d_in[1];
  const float* Wq   = (const float*)d_in[2];
  const float* bq   = (const float*)d_in[3];
  const float* Wk   = (const float*)d_in[4];
  const float* bk   = (const float*)d_in[5];
  const float* Wv   = (const float*)d_in[6];
  const float* bv   = (const float*)d_in[7];
  const float* Wh   = (const float*)d_in[8];
  const float* bh   = (const float*)d_in[9];
  const float* Wout = (const float*)d_in[10];
  const float* W1   = (const float*)d_in[11];
  const float* b1   = (const float*)d_in[12];
  const float* W2   = (const float*)d_in[13];
  const float* b2   = (const float*)d_in[14];
  const float* Wc1  = (const float*)d_in[15];
  const float* bc1  = (const float*)d_in[16];
  const float* Wc2  = (const float*)d_in[17];
  const float* bc2  = (const float*)d_in[18];

  const int B = in_sizes[1];  // 2048
  float* wsf = (float*)d_ws;
  float* out = (float*)d_out;

  encoder_kernel<<<B, 64, 0, stream>>>(emb, labels, Wq, bq, Wk, bk, Wv, bv,
                                       Wh, bh, Wout, W1, b1, W2, b2,
                                       Wc1, bc1, Wc2, bc2, wsf, wsf + B);
  reduce_kernel<<<1, 256, 0, stream>>>(wsf, wsf + B, out, B);
}

// Round 2
// 3552.189 us; speedup vs baseline: 1.3499x; 1.3499x over previous
//
#include <hip/hip_runtime.h>
#include <math.h>

namespace {

constexpr int D    = 49;   // dim == num_patches
constexpr int H    = 8;
constexpr int L    = 4;
constexpr int ST   = 56;   // bf16 row stride (elements): 112 B, 16 B-aligned
constexpr int HID  = 25;
constexpr int NCLS = 10;

// ---- bf16 (stored as ushort) <-> f32 helpers ----
__device__ __forceinline__ float bf2f(unsigned short s) {
  return __uint_as_float(((unsigned)s) << 16);
}
__device__ __forceinline__ unsigned short f2bf(float x) {  // RNE
  unsigned u = __float_as_uint(x);
  return (unsigned short)((u + 0x7FFFu + ((u >> 16) & 1u)) >> 16);
}
__device__ __forceinline__ float bflo(unsigned u) { return __uint_as_float(u << 16); }
__device__ __forceinline__ float bfhi(unsigned u) { return __uint_as_float(u & 0xFFFF0000u); }

__device__ __forceinline__ void unpack8(uint4 u, float* f) {
  f[0] = bflo(u.x); f[1] = bfhi(u.x); f[2] = bflo(u.y); f[3] = bfhi(u.y);
  f[4] = bflo(u.z); f[5] = bfhi(u.z); f[6] = bflo(u.w); f[7] = bfhi(u.w);
}

// acc[0..48] += row(bf16,49 elems) @ W(f32, 49x49 row-major); W wave-uniform (s_load stream).
// k tiled by 8: 1 ds_read_b128 -> 8 statically-indexed a[t], 392 FMAs per body.
__device__ __forceinline__ void mm_row(const unsigned short* row,
                                       const float* __restrict__ wp,
                                       float* acc) {
  #pragma unroll 1
  for (int kk = 0; kk < 48; kk += 8) {
    float a[8];
    unpack8(*reinterpret_cast<const uint4*>(row + kk), a);
    #pragma unroll
    for (int t = 0; t < 8; ++t) {
      const float* w = wp + (kk + t) * D;
      #pragma unroll
      for (int e = 0; e < D; ++e) acc[e] = fmaf(a[t], w[e], acc[e]);
    }
  }
  const float a = bf2f(row[48]);
  const float* w = wp + 48 * D;
  #pragma unroll
  for (int e = 0; e < D; ++e) acc[e] = fmaf(a, w[e], acc[e]);
}

// s = dot(q[0..48], row bf16[0..48])
__device__ __forceinline__ float dot49(const float* q, const unsigned short* row) {
  const uint4* r4 = reinterpret_cast<const uint4*>(row);
  float s = 0.0f, f[8];
  #pragma unroll
  for (int g = 0; g < 6; ++g) {
    unpack8(r4[g], f);
    #pragma unroll
    for (int e = 0; e < 8; ++e) s = fmaf(q[8 * g + e], f[e], s);
  }
  return fmaf(q[48], bf2f(row[48]), s);
}

// c[0..48] += p * row(bf16)
__device__ __forceinline__ void axpy49(float p, const unsigned short* row, float* c) {
  const uint4* r4 = reinterpret_cast<const uint4*>(row);
  float f[8];
  #pragma unroll
  for (int g = 0; g < 6; ++g) {
    unpack8(r4[g], f);
    #pragma unroll
    for (int e = 0; e < 8; ++e) c[8 * g + e] = fmaf(p, f[e], c[8 * g + e]);
  }
  c[48] = fmaf(p, bf2f(row[48]), c[48]);
}

// f32[49] -> bf16 row, packed b32 stores
__device__ __forceinline__ void store_row(unsigned short* row, const float* v) {
  unsigned* r32 = reinterpret_cast<unsigned*>(row);
  #pragma unroll
  for (int g = 0; g < 24; ++g)
    r32[g] = (unsigned)f2bf(v[2 * g]) | ((unsigned)f2bf(v[2 * g + 1]) << 16);
  row[48] = f2bf(v[48]);
}

__global__ void __launch_bounds__(64)
encoder_kernel(const float* __restrict__ emb, const int* __restrict__ labels,
               const float* __restrict__ Wq, const float* __restrict__ bq,
               const float* __restrict__ Wk, const float* __restrict__ bk,
               const float* __restrict__ Wv, const float* __restrict__ bv,
               const float* __restrict__ Wh, const float* __restrict__ bh,
               const float* __restrict__ Wout,
               const float* __restrict__ W1, const float* __restrict__ b1,
               const float* __restrict__ W2, const float* __restrict__ b2,
               const float* __restrict__ Wc1, const float* __restrict__ bc1,
               const float* __restrict__ Wc2, const float* __restrict__ bc2,
               float* __restrict__ ws_loss, float* __restrict__ ws_corr) {
  __shared__ __align__(16) unsigned short X[D * ST];   // residual stream (bf16)
  __shared__ __align__(16) unsigned short KB[D * ST];  // K rows / ho / od staging
  __shared__ __align__(16) unsigned short VB[D * ST];  // V rows / ctx / t staging
  __shared__ float CLS[128];                           // f32 classifier scratch

  const int b    = blockIdx.x;
  const int lane = threadIdx.x;                 // block == 1 wave
  const int ii   = lane < D ? lane : (D - 1);   // lanes 49..63 mirror row 48
  const bool wr  = lane < D;                    // only real rows write LDS

  for (int idx = lane; idx < D * D; idx += 64) {
    const int r = idx / D, c = idx - r * D;
    X[r * ST + c] = f2bf(emb[(size_t)b * (D * D) + idx]);
  }
  __syncthreads();

  const float invSCALE = 1.0f / (7.0f + 1e-6f);

  #pragma unroll 1
  for (int l = 0; l < L; ++l) {
    float od[D];
    #pragma unroll
    for (int e = 0; e < D; ++e) od[e] = 0.0f;

    #pragma unroll 1
    for (int h = 0; h < H; ++h) {
      const int lh = l * H + h;
      const float* wqp = Wq + (size_t)lh * D * D;
      const float* wkp = Wk + (size_t)lh * D * D;
      const float* wvp = Wv + (size_t)lh * D * D;
      const float* whp = Wh + (size_t)lh * D * D;
      const float* wop = Wout + (size_t)lh * D * D;

      {  // K row -> KB
        float kr[D];
        const float* bp = bk + lh * D;
        #pragma unroll
        for (int e = 0; e < D; ++e) kr[e] = bp[e];
        mm_row(&X[ii * ST], wkp, kr);
        if (wr) store_row(&KB[ii * ST], kr);
      }
      {  // V row -> VB
        float vr[D];
        const float* bp = bv + lh * D;
        #pragma unroll
        for (int e = 0; e < D; ++e) vr[e] = bp[e];
        mm_row(&X[ii * ST], wvp, vr);
        if (wr) store_row(&VB[ii * ST], vr);
      }
      float q[D];
      {  // Q row in registers
        const float* bp = bq + lh * D;
        #pragma unroll
        for (int e = 0; e < D; ++e) q[e] = bp[e];
        mm_row(&X[ii * ST], wqp, q);
      }
      __syncthreads();

      // fused scores + online softmax (defer-max THR=8) + PV
      float ctx[D];
      #pragma unroll
      for (int e = 0; e < D; ++e) ctx[e] = 0.0f;
      float m = -INFINITY, den = 0.0f;

      #pragma unroll 1
      for (int j = 0; j < D; ++j) {
        float s = dot49(q, &KB[j * ST]) * invSCALE;
        s = fminf(fmaxf(s, -30.0f), 30.0f);
        if (s > m + 8.0f) {
          const float r = __expf(m - s);  // expf(-inf)=0 covers first iter
          den *= r;
          #pragma unroll
          for (int e = 0; e < D; ++e) ctx[e] *= r;
          m = s;
        }
        const float p = __expf(s - m);
        den += p;
        axpy49(p, &VB[j * ST], ctx);
      }
      const float invden = 1.0f / den;
      #pragma unroll
      for (int e = 0; e < D; ++e) ctx[e] *= invden;
      __syncthreads();  // all lanes done reading KB/VB before overwrite

      if (wr) store_row(&VB[ii * ST], ctx);
      float ho[D];
      {  // ho = ctx @ Wh + bh
        const float* bp = bh + lh * D;
        #pragma unroll
        for (int o = 0; o < D; ++o) ho[o] = bp[o];
        mm_row(&VB[ii * ST], whp, ho);
      }
      if (wr) store_row(&KB[ii * ST], ho);
      mm_row(&KB[ii * ST], wop, od);  // od += ho @ Wout
    }  // heads

    // MLP between blocks (no activation)
    if (wr) store_row(&KB[ii * ST], od);
    float t[D];
    {
      const float* bp = b1 + l * D;
      #pragma unroll
      for (int jj = 0; jj < D; ++jj) t[jj] = bp[jj];
      mm_row(&KB[ii * ST], W1 + (size_t)l * D * D, t);
    }
    if (wr) store_row(&VB[ii * ST], t);
    float x2[D];
    {
      const float* bp = b2 + l * D;
      #pragma unroll
      for (int jj = 0; jj < D; ++jj) x2[jj] = bp[jj];
      mm_row(&VB[ii * ST], W2 + (size_t)l * D * D, x2);
    }
    __syncthreads();
    if (wr) store_row(&X[ii * ST], x2);
    __syncthreads();
  }  // layers

  // ---- classifier head (f32 scratch) ----
  if (lane < D) {
    float s = 0.0f;
    #pragma unroll 1
    for (int r = 0; r < D; ++r) s += bf2f(X[r * ST + lane]);
    CLS[lane] = s * (1.0f / 49.0f);  // pooled
  }
  __syncthreads();
  if (lane < HID) {
    float acc = bc1[lane];
    #pragma unroll 1
    for (int d = 0; d < D; ++d) acc = fmaf(CLS[d], Wc1[d * HID + lane], acc);
    CLS[64 + lane] = acc;  // hidden
  }
  __syncthreads();
  if (lane < NCLS) {
    float acc = bc2[lane];
    #pragma unroll 1
    for (int j = 0; j < HID; ++j) acc = fmaf(CLS[64 + j], Wc2[j * NCLS + lane], acc);
    CLS[96 + lane] = acc;  // logits
  }
  __syncthreads();
  if (lane == 0) {
    float mx = CLS[96];
    int am = 0;
    #pragma unroll 1
    for (int c = 1; c < NCLS; ++c) {
      const float v = CLS[96 + c];
      if (v > mx) { mx = v; am = c; }  // strict '>' == first max (jnp.argmax)
    }
    float se = 0.0f;
    #pragma unroll 1
    for (int c = 0; c < NCLS; ++c) se += expf(CLS[96 + c] - mx);
    const float lse = mx + logf(se);
    const int lbl = labels[b];
    ws_loss[b] = lse - CLS[96 + lbl];
    ws_corr[b] = (am == lbl) ? 1.0f : 0.0f;
  }
}

__global__ void __launch_bounds__(256)
reduce_kernel(const float* __restrict__ wsl, const float* __restrict__ wsc,
              float* __restrict__ out, int n) {
  __shared__ float sl[256];
  __shared__ float sc[256];
  const int t = threadIdx.x;
  float a = 0.0f, c = 0.0f;
  for (int idx = t; idx < n; idx += 256) { a += wsl[idx]; c += wsc[idx]; }
  sl[t] = a; sc[t] = c;
  __syncthreads();
  for (int s = 128; s > 0; s >>= 1) {
    if (t < s) { sl[t] += sl[t + s]; sc[t] += sc[t + s]; }
    __syncthreads();
  }
  if (t == 0) {
    out[0] = sl[0] / (float)n;  // loss
    out[1] = sc[0] / (float)n;  // accuracy
  }
}

}  // namespace

extern "C" void kernel_launch(void* const* d_in, const int* in_sizes, int n_in,
                              void* d_out, int out_size, void* d_ws, size_t ws_size,
                              hipStream_t stream) {
  const float* emb    = (const float*)d_in[0];
  const int*   labels = (const int*)d_in[1];
  const float* Wq   = (const float*)d_in[2];
  const float* bq   = (const float*)d_in[3];
  const float* Wk   = (const float*)d_in[4];
  const float* bk   = (const float*)d_in[5];
  const float* Wv   = (const float*)d_in[6];
  const float* bv   = (const float*)d_in[7];
  const float* Wh   = (const float*)d_in[8];
  const float* bh   = (const float*)d_in[9];
  const float* Wout = (const float*)d_in[10];
  const float* W1   = (const float*)d_in[11];
  const float* b1   = (const float*)d_in[12];
  const float* W2   = (const float*)d_in[13];
  const float* b2   = (const float*)d_in[14];
  const float* Wc1  = (const float*)d_in[15];
  const float* bc1  = (const float*)d_in[16];
  const float* Wc2  = (const float*)d_in[17];
  const float* bc2  = (const float*)d_in[18];

  const int B = in_sizes[1];  // 2048
  float* wsf = (float*)d_ws;
  float* out = (float*)d_out;

  encoder_kernel<<<B, 64, 0, stream>>>(emb, labels, Wq, bq, Wk, bk, Wv, bv,
                                       Wh, bh, Wout, W1, b1, W2, b2,
                                       Wc1, bc1, Wc2, bc2, wsf, wsf + B);
  reduce_kernel<<<1, 256, 0, stream>>>(wsf, wsf + B, out, B);
}

// Round 4
// 366.976 us; speedup vs baseline: 13.0662x; 9.6796x over previous
//
#include <hip/hip_runtime.h>
#include <math.h>

namespace {

constexpr int D    = 49;
constexpr int H    = 8;
constexpr int L    = 4;
constexpr int HID  = 25;
constexpr int NCLS = 10;
constexpr int XS   = 68;    // LDS X row stride (bf16 elems)
constexpr int WSM  = 4096;  // ushorts per padded 64x64 matrix in chunk-frag layout
constexpr float NEGBIG = -1e30f;  // finite mask: exp(NEGBIG - mx) == 0, no inf-inf

typedef __attribute__((ext_vector_type(4))) short short4v;
typedef __attribute__((ext_vector_type(8))) short short8v;
typedef __attribute__((ext_vector_type(4))) float float4v;
typedef __attribute__((ext_vector_type(4))) __bf16 bf16x4;

// One 16x16x32 bf16 MFMA; operands = concat of two 4-elem k-chunks.
// Consistent A/B chunk packing => correct contraction regardless of HW k-map.
__device__ __forceinline__ float4v mfma32(short4v alo, short4v ahi,
                                          short4v blo, short4v bhi, float4v c) {
  short8v a = __builtin_shufflevector(alo, ahi, 0, 1, 2, 3, 4, 5, 6, 7);
  short8v b = __builtin_shufflevector(blo, bhi, 0, 1, 2, 3, 4, 5, 6, 7);
  return __builtin_amdgcn_mfma_f32_16x16x32_bf16(a, b, c, 0, 0, 0);
}

__device__ __forceinline__ unsigned short f2bf(float x) {  // RNE bit-twiddle
  unsigned u = __float_as_uint(x);
  return (unsigned short)((u + 0x7FFFu + ((u >> 16) & 1u)) >> 16);
}

__device__ __forceinline__ short4v cvt4(float4v v) {  // 4xf32 -> 4xbf16 (compiler cvt)
  bf16x4 b = {(__bf16)v[0], (__bf16)v[1], (__bf16)v[2], (__bf16)v[3]};
  return __builtin_bit_cast(short4v, b);
}

__device__ __forceinline__ float4v splat4(float x) {
  float4v v; v[0] = x; v[1] = x; v[2] = x; v[3] = x; return v;
}

// chunk-frag (ktc, nt) of a prepped 64x64 matrix: semantic k = 16*ktc+4*g+j, col = 16*nt+c
__device__ __forceinline__ short4v wsld(const unsigned short* __restrict__ w,
                                        int ktc, int nt, int lane) {
  return *reinterpret_cast<const short4v*>(w + ((ktc * 4 + nt) * 64 + lane) * 4);
}

__device__ __forceinline__ float4v rowbias(const float* __restrict__ bp, int mt, int g) {
  float4v r;
  #pragma unroll
  for (int i = 0; i < 4; ++i) {
    const int e = 16 * mt + 4 * g + i;
    r[i] = (e < D) ? bp[e] : 0.0f;
  }
  return r;
}

// acc(cfrag of OUT^T) = W^T @ SRC + rowbias, K=32 MFMA over chunk pairs
__device__ __forceinline__ void mmT(const unsigned short* __restrict__ w,
                                    const short4v (&src)[4][4],
                                    const float* __restrict__ bp,
                                    int g, int lane, float4v (&acc)[4][4]) {
  #pragma unroll
  for (int mt = 0; mt < 4; ++mt) {
    const float4v rb = rowbias(bp, mt, g);
    #pragma unroll
    for (int nt = 0; nt < 4; ++nt) acc[mt][nt] = rb;
  }
  #pragma unroll
  for (int k2 = 0; k2 < 2; ++k2) {
    short4v alo[4], ahi[4];
    #pragma unroll
    for (int mt = 0; mt < 4; ++mt) {
      alo[mt] = wsld(w, 2 * k2,     mt, lane);
      ahi[mt] = wsld(w, 2 * k2 + 1, mt, lane);
    }
    #pragma unroll
    for (int nt = 0; nt < 4; ++nt)
      #pragma unroll
      for (int mt = 0; mt < 4; ++mt)
        acc[mt][nt] = mfma32(alo[mt], ahi[mt],
                             src[2 * k2][nt], src[2 * k2 + 1][nt], acc[mt][nt]);
  }
}

// Pre-shuffle one 49x49 f32 matrix into padded 64x64 bf16 chunk-frag layout.
__global__ void __launch_bounds__(256)
prep_weights(const float* __restrict__ Wq, const float* __restrict__ Wk,
             const float* __restrict__ Wv, const float* __restrict__ Wh,
             const float* __restrict__ Wout, const float* __restrict__ W1,
             const float* __restrict__ W2, unsigned short* __restrict__ ws) {
  const int m = blockIdx.x;  // 0..167
  const float* src;
  if (m < 32)       src = Wq   + (size_t)m * D * D;
  else if (m < 64)  src = Wk   + (size_t)(m - 32) * D * D;
  else if (m < 96)  src = Wv   + (size_t)(m - 64) * D * D;
  else if (m < 128) src = Wh   + (size_t)(m - 96) * D * D;
  else if (m < 160) src = Wout + (size_t)(m - 128) * D * D;
  else if (m < 164) src = W1   + (size_t)(m - 160) * D * D;
  else              src = W2   + (size_t)(m - 164) * D * D;

  const int t = threadIdx.x;
  const int ktc = t >> 6, lane = t & 63;
  const int gg = lane >> 4, cc = lane & 15;
  #pragma unroll
  for (int nt = 0; nt < 4; ++nt) {
    short4v v;
    #pragma unroll
    for (int j = 0; j < 4; ++j) {
      const int k = 16 * ktc + 4 * gg + j;
      const int n = 16 * nt + cc;
      const float f = (k < D && n < D) ? src[k * D + n] : 0.0f;
      v[j] = (short)f2bf(f);
    }
    *reinterpret_cast<short4v*>(ws + (size_t)m * WSM + ((ktc * 4 + nt) * 64 + lane) * 4) = v;
  }
}

__global__ void __launch_bounds__(64, 2)
encoder_kernel(const float* __restrict__ emb, const int* __restrict__ labels,
               const unsigned short* __restrict__ ws,
               const float* __restrict__ bq, const float* __restrict__ bk,
               const float* __restrict__ bv, const float* __restrict__ bh,
               const float* __restrict__ b1, const float* __restrict__ b2,
               const float* __restrict__ Wc1, const float* __restrict__ bc1,
               const float* __restrict__ Wc2, const float* __restrict__ bc2,
               float* __restrict__ ws_loss, float* __restrict__ ws_corr) {
  __shared__ unsigned short X[64 * XS];  // residual stream, [row][col] bf16
  __shared__ float CLS[128];

  const int b = blockIdx.x;
  const int lane = threadIdx.x;          // one wave per block
  const int g = lane >> 4, c = lane & 15;

  // ---- X <- embedding (zero-padded to 64x64) ----
  for (int idx = lane; idx < 64 * 64; idx += 64) {
    const int r = idx >> 6, cc = idx & 63;
    const float v = (r < D && cc < D) ? emb[(size_t)b * (D * D) + r * D + cc] : 0.0f;
    X[r * XS + cc] = f2bf(v);
  }
  __syncthreads();

  const float invSCALE = 1.0f / (7.0f + 1e-6f);

  short4v xf[4][4];    // xf[ktc][mt]: X[16mt+c][16ktc+4g..+3] (A-chunk of X)
  float4v xacc[4][4];  // layer output cfrag (kept for pooling)

  #pragma unroll 1
  for (int l = 0; l < L; ++l) {
    #pragma unroll
    for (int ktc = 0; ktc < 4; ++ktc)
      #pragma unroll
      for (int mt = 0; mt < 4; ++mt)
        xf[ktc][mt] = *reinterpret_cast<const short4v*>(
            &X[(16 * mt + c) * XS + 16 * ktc + 4 * g]);

    float4v od[4][4];  // od^T f32 accumulator across heads
    #pragma unroll
    for (int mt = 0; mt < 4; ++mt)
      #pragma unroll
      for (int nt = 0; nt < 4; ++nt) od[mt][nt] = splat4(0.0f);

    #pragma unroll 1
    for (int h = 0; h < H; ++h) {
      const int lh = l * H + h;
      const unsigned short* wq = ws + (size_t)(0   + lh) * WSM;
      const unsigned short* wk = ws + (size_t)(32  + lh) * WSM;
      const unsigned short* wv = ws + (size_t)(64  + lh) * WSM;
      const unsigned short* wh = ws + (size_t)(96  + lh) * WSM;
      const unsigned short* wo = ws + (size_t)(128 + lh) * WSM;

      // ---- Q^T, K^T (cfrag; rows = e dim = next contraction chunk) ----
      float4v qa[4][4], ka[4][4];
      mmT(wq, xf, bq + lh * D, g, lane, qa);
      mmT(wk, xf, bk + lh * D, g, lane, ka);
      short4v qf[4][4], kf[4][4];
      #pragma unroll
      for (int mt = 0; mt < 4; ++mt)
        #pragma unroll
        for (int nt = 0; nt < 4; ++nt) { qf[mt][nt] = cvt4(qa[mt][nt]); kf[mt][nt] = cvt4(ka[mt][nt]); }

      // ---- S^T = K @ Q^T ----
      float4v s[4][4];
      #pragma unroll
      for (int mt = 0; mt < 4; ++mt)
        #pragma unroll
        for (int nt = 0; nt < 4; ++nt) s[mt][nt] = splat4(0.0f);
      #pragma unroll
      for (int k2 = 0; k2 < 2; ++k2)
        #pragma unroll
        for (int nt = 0; nt < 4; ++nt)
          #pragma unroll
          for (int mt = 0; mt < 4; ++mt)
            s[mt][nt] = mfma32(kf[2 * k2][mt], kf[2 * k2 + 1][mt],
                               qf[2 * k2][nt], qf[2 * k2 + 1][nt], s[mt][nt]);

      // ---- scale, clip, mask pad keys j=16mt+4g+r>=49, softmax over j ----
      #pragma unroll
      for (int mt = 0; mt < 4; ++mt)
        #pragma unroll
        for (int nt = 0; nt < 4; ++nt)
          #pragma unroll
          for (int r = 0; r < 4; ++r) {
            float sv = s[mt][nt][r] * invSCALE;
            sv = fminf(fmaxf(sv, -30.0f), 30.0f);
            if (mt == 3) sv = (r == 0 && g == 0) ? sv : NEGBIG;
            s[mt][nt][r] = sv;
          }
      float inv_[4];
      #pragma unroll
      for (int nt = 0; nt < 4; ++nt) {
        float mx = s[0][nt][0];
        #pragma unroll
        for (int mt = 0; mt < 4; ++mt)
          #pragma unroll
          for (int r = 0; r < 4; ++r) mx = fmaxf(mx, s[mt][nt][r]);
        mx = fmaxf(mx, __shfl_xor(mx, 16));
        mx = fmaxf(mx, __shfl_xor(mx, 32));
        float dn = 0.0f;
        #pragma unroll
        for (int mt = 0; mt < 4; ++mt)
          #pragma unroll
          for (int r = 0; r < 4; ++r) {
            const float p = __expf(s[mt][nt][r] - mx);
            s[mt][nt][r] = p;
            dn += p;
          }
        dn += __shfl_xor(dn, 16);
        dn += __shfl_xor(dn, 32);
        inv_[nt] = 1.0f / fmaxf(dn, 1e-37f);
      }
      short4v pf[4][4];
      #pragma unroll
      for (int mt = 0; mt < 4; ++mt)
        #pragma unroll
        for (int nt = 0; nt < 4; ++nt) pf[mt][nt] = cvt4(s[mt][nt]);

      // ---- V = X @ Wv + bv (cfrag(V); rows = patch, cols = e) ----
      float4v va[4][4];
      #pragma unroll
      for (int nt = 0; nt < 4; ++nt) {
        const int e = 16 * nt + c;
        const float bvv = (e < D) ? bv[lh * D + e] : 0.0f;
        #pragma unroll
        for (int mt = 0; mt < 4; ++mt) va[mt][nt] = splat4(bvv);
      }
      #pragma unroll
      for (int k2 = 0; k2 < 2; ++k2) {
        short4v blo[4], bhi[4];
        #pragma unroll
        for (int nt = 0; nt < 4; ++nt) {
          blo[nt] = wsld(wv, 2 * k2,     nt, lane);
          bhi[nt] = wsld(wv, 2 * k2 + 1, nt, lane);
        }
        #pragma unroll
        for (int nt = 0; nt < 4; ++nt)
          #pragma unroll
          for (int mt = 0; mt < 4; ++mt)
            va[mt][nt] = mfma32(xf[2 * k2][mt], xf[2 * k2 + 1][mt],
                                blo[nt], bhi[nt], va[mt][nt]);
      }
      short4v vf[4][4];
      #pragma unroll
      for (int mt = 0; mt < 4; ++mt)
        #pragma unroll
        for (int nt = 0; nt < 4; ++nt) vf[mt][nt] = cvt4(va[mt][nt]);

      // ---- ctx^T = V^T @ P^T, then * inv_den per column ----
      float4v ca[4][4];
      #pragma unroll
      for (int mt = 0; mt < 4; ++mt)
        #pragma unroll
        for (int nt = 0; nt < 4; ++nt) ca[mt][nt] = splat4(0.0f);
      #pragma unroll
      for (int k2 = 0; k2 < 2; ++k2)
        #pragma unroll
        for (int nt = 0; nt < 4; ++nt)
          #pragma unroll
          for (int mt = 0; mt < 4; ++mt)
            ca[mt][nt] = mfma32(vf[2 * k2][mt], vf[2 * k2 + 1][mt],
                                pf[2 * k2][nt], pf[2 * k2 + 1][nt], ca[mt][nt]);
      short4v cf[4][4];
      #pragma unroll
      for (int mt = 0; mt < 4; ++mt)
        #pragma unroll
        for (int nt = 0; nt < 4; ++nt) cf[mt][nt] = cvt4(ca[mt][nt] * inv_[nt]);

      // ---- ho^T = Wh^T @ ctx^T + bh ----
      float4v ha[4][4];
      mmT(wh, cf, bh + lh * D, g, lane, ha);
      short4v hf[4][4];
      #pragma unroll
      for (int mt = 0; mt < 4; ++mt)
        #pragma unroll
        for (int nt = 0; nt < 4; ++nt) hf[mt][nt] = cvt4(ha[mt][nt]);

      // ---- od^T += Wout^T @ ho^T ----
      #pragma unroll
      for (int k2 = 0; k2 < 2; ++k2) {
        short4v alo[4], ahi[4];
        #pragma unroll
        for (int mt = 0; mt < 4; ++mt) {
          alo[mt] = wsld(wo, 2 * k2,     mt, lane);
          ahi[mt] = wsld(wo, 2 * k2 + 1, mt, lane);
        }
        #pragma unroll
        for (int nt = 0; nt < 4; ++nt)
          #pragma unroll
          for (int mt = 0; mt < 4; ++mt)
            od[mt][nt] = mfma32(alo[mt], ahi[mt],
                                hf[2 * k2][nt], hf[2 * k2 + 1][nt], od[mt][nt]);
      }
    }  // heads

    // ---- MLP: t^T = W1^T @ od^T + b1; x_new = t @ W2 + b2 ----
    short4v of[4][4];
    #pragma unroll
    for (int mt = 0; mt < 4; ++mt)
      #pragma unroll
      for (int nt = 0; nt < 4; ++nt) of[mt][nt] = cvt4(od[mt][nt]);
    float4v ta[4][4];
    mmT(ws + (size_t)(160 + l) * WSM, of, b1 + l * D, g, lane, ta);
    short4v tf[4][4];
    #pragma unroll
    for (int mt = 0; mt < 4; ++mt)
      #pragma unroll
      for (int nt = 0; nt < 4; ++nt) tf[mt][nt] = cvt4(ta[mt][nt]);

    const unsigned short* w2p = ws + (size_t)(164 + l) * WSM;
    #pragma unroll
    for (int nt = 0; nt < 4; ++nt) {
      const int e = 16 * nt + c;
      const float bvv = (e < D) ? b2[l * D + e] : 0.0f;
      #pragma unroll
      for (int mt = 0; mt < 4; ++mt) xacc[mt][nt] = splat4(bvv);
    }
    #pragma unroll
    for (int k2 = 0; k2 < 2; ++k2) {
      short4v blo[4], bhi[4];
      #pragma unroll
      for (int nt = 0; nt < 4; ++nt) {
        blo[nt] = wsld(w2p, 2 * k2,     nt, lane);
        bhi[nt] = wsld(w2p, 2 * k2 + 1, nt, lane);
      }
      #pragma unroll
      for (int nt = 0; nt < 4; ++nt)
        #pragma unroll
        for (int mt = 0; mt < 4; ++mt)
          xacc[mt][nt] = mfma32(tf[2 * k2][mt], tf[2 * k2 + 1][mt],
                                blo[nt], bhi[nt], xacc[mt][nt]);
    }

    if (l < L - 1) {
      __syncthreads();
      #pragma unroll
      for (int mt = 0; mt < 4; ++mt)
        #pragma unroll
        for (int nt = 0; nt < 4; ++nt)
          #pragma unroll
          for (int r = 0; r < 4; ++r)
            X[(16 * mt + 4 * g + r) * XS + 16 * nt + c] = f2bf(xacc[mt][nt][r]);
      __syncthreads();
    }
  }  // layers

  // ---- pooled = mean over rows<49 ----
  float ps[4];
  #pragma unroll
  for (int nt = 0; nt < 4; ++nt) {
    float sum = 0.0f;
    #pragma unroll
    for (int mt = 0; mt < 3; ++mt)
      #pragma unroll
      for (int r = 0; r < 4; ++r) sum += xacc[mt][nt][r];
    if (g == 0) sum += xacc[3][nt][0];  // row 48
    sum += __shfl_xor(sum, 16);
    sum += __shfl_xor(sum, 32);
    ps[nt] = sum * (1.0f / 49.0f);
  }
  if (lane < 16) {
    #pragma unroll
    for (int nt = 0; nt < 4; ++nt) CLS[16 * nt + lane] = ps[nt];
  }
  __syncthreads();

  if (lane < HID) {
    float acc = bc1[lane];
    #pragma unroll 1
    for (int d = 0; d < D; ++d) acc = fmaf(CLS[d], Wc1[d * HID + lane], acc);
    CLS[64 + lane] = acc;
  }
  __syncthreads();
  if (lane < NCLS) {
    float acc = bc2[lane];
    #pragma unroll 1
    for (int j = 0; j < HID; ++j) acc = fmaf(CLS[64 + j], Wc2[j * NCLS + lane], acc);
    CLS[96 + lane] = acc;
  }
  __syncthreads();
  if (lane == 0) {
    float mx = CLS[96];
    int am = 0;
    #pragma unroll 1
    for (int cc = 1; cc < NCLS; ++cc) {
      const float v = CLS[96 + cc];
      if (v > mx) { mx = v; am = cc; }  // strict '>' == first max (jnp.argmax)
    }
    float se = 0.0f;
    #pragma unroll 1
    for (int cc = 0; cc < NCLS; ++cc) se += expf(CLS[96 + cc] - mx);
    const float lse = mx + logf(se);
    const int lbl = labels[b];
    ws_loss[b] = lse - CLS[96 + lbl];
    ws_corr[b] = (am == lbl) ? 1.0f : 0.0f;
  }
}

__global__ void __launch_bounds__(256)
reduce_kernel(const float* __restrict__ wsl, const float* __restrict__ wsc,
              float* __restrict__ out, int n) {
  __shared__ float sl[256];
  __shared__ float sc[256];
  const int t = threadIdx.x;
  float a = 0.0f, cc = 0.0f;
  for (int idx = t; idx < n; idx += 256) { a += wsl[idx]; cc += wsc[idx]; }
  sl[t] = a; sc[t] = cc;
  __syncthreads();
  for (int s = 128; s > 0; s >>= 1) {
    if (t < s) { sl[t] += sl[t + s]; sc[t] += sc[t + s]; }
    __syncthreads();
  }
  if (t == 0) {
    out[0] = sl[0] / (float)n;
    out[1] = sc[0] / (float)n;
  }
}

}  // namespace

extern "C" void kernel_launch(void* const* d_in, const int* in_sizes, int n_in,
                              void* d_out, int out_size, void* d_ws, size_t ws_size,
                              hipStream_t stream) {
  const float* emb    = (const float*)d_in[0];
  const int*   labels = (const int*)d_in[1];
  const float* Wq   = (const float*)d_in[2];
  const float* bq   = (const float*)d_in[3];
  const float* Wk   = (const float*)d_in[4];
  const float* bk   = (const float*)d_in[5];
  const float* Wv   = (const float*)d_in[6];
  const float* bv   = (const float*)d_in[7];
  const float* Wh   = (const float*)d_in[8];
  const float* bh   = (const float*)d_in[9];
  const float* Wout = (const float*)d_in[10];
  const float* W1   = (const float*)d_in[11];
  const float* b1   = (const float*)d_in[12];
  const float* W2   = (const float*)d_in[13];
  const float* b2   = (const float*)d_in[14];
  const float* Wc1  = (const float*)d_in[15];
  const float* bc1  = (const float*)d_in[16];
  const float* Wc2  = (const float*)d_in[17];
  const float* bc2  = (const float*)d_in[18];

  const int B = in_sizes[1];  // 2048
  const size_t wBytes = (size_t)168 * WSM * sizeof(unsigned short);
  const size_t need = wBytes + (size_t)2 * B * sizeof(float);
  if (ws_size < need) return;

  unsigned short* wsb = (unsigned short*)d_ws;
  float* wsf = (float*)((char*)d_ws + wBytes);
  float* out = (float*)d_out;

  prep_weights<<<168, 256, 0, stream>>>(Wq, Wk, Wv, Wh, Wout, W1, W2, wsb);
  encoder_kernel<<<B, 64, 0, stream>>>(emb, labels, wsb, bq, bk, bv, bh,
                                       b1, b2, Wc1, bc1, Wc2, bc2,
                                       wsf, wsf + B);
  reduce_kernel<<<1, 256, 0, stream>>>(wsf, wsf + B, out, B);
}

// Round 5
// 366.508 us; speedup vs baseline: 13.0829x; 1.0013x over previous
//
#include <hip/hip_runtime.h>
#include <math.h>

namespace {

constexpr int D    = 49;
constexpr int H    = 8;
constexpr int L    = 4;
constexpr int HID  = 25;
constexpr int NCLS = 10;
constexpr int XS   = 68;    // LDS X row stride (bf16 elems)
constexpr int WSM  = 4096;  // ushorts per padded 64x64 matrix in chunk-frag layout
constexpr float NEGBIG = -1e30f;  // finite mask: exp(NEGBIG - mx) == 0, no inf-inf

typedef __attribute__((ext_vector_type(4))) short short4v;
typedef __attribute__((ext_vector_type(8))) short short8v;
typedef __attribute__((ext_vector_type(4))) float float4v;
typedef __attribute__((ext_vector_type(4))) __bf16 bf16x4;

// One 16x16x32 bf16 MFMA; operands = concat of two 4-elem k-chunks.
// Consistent A/B chunk packing => correct contraction regardless of HW k-map.
__device__ __forceinline__ float4v mfma32(short4v alo, short4v ahi,
                                          short4v blo, short4v bhi, float4v c) {
  short8v a = __builtin_shufflevector(alo, ahi, 0, 1, 2, 3, 4, 5, 6, 7);
  short8v b = __builtin_shufflevector(blo, bhi, 0, 1, 2, 3, 4, 5, 6, 7);
  return __builtin_amdgcn_mfma_f32_16x16x32_bf16(a, b, c, 0, 0, 0);
}

__device__ __forceinline__ unsigned short f2bf(float x) {  // RNE bit-twiddle
  unsigned u = __float_as_uint(x);
  return (unsigned short)((u + 0x7FFFu + ((u >> 16) & 1u)) >> 16);
}

__device__ __forceinline__ short4v cvt4(float4v v) {  // 4xf32 -> 4xbf16 (compiler cvt)
  bf16x4 b = {(__bf16)v[0], (__bf16)v[1], (__bf16)v[2], (__bf16)v[3]};
  return __builtin_bit_cast(short4v, b);
}

__device__ __forceinline__ float4v splat4(float x) {
  float4v v; v[0] = x; v[1] = x; v[2] = x; v[3] = x; return v;
}

// chunk-frag (ktc, nt) of a prepped 64x64 matrix: semantic k = 16*ktc+4*g+j, col = 16*nt+c
__device__ __forceinline__ short4v wsld(const unsigned short* __restrict__ w,
                                        int ktc, int nt, int lane) {
  return *reinterpret_cast<const short4v*>(w + ((ktc * 4 + nt) * 64 + lane) * 4);
}

__device__ __forceinline__ float4v rowbias(const float* __restrict__ bp, int mt, int g) {
  float4v r;
  #pragma unroll
  for (int i = 0; i < 4; ++i) {
    const int e = 16 * mt + 4 * g + i;
    r[i] = (e < D) ? bp[e] : 0.0f;
  }
  return r;
}

// acc(cfrag of OUT^T) = W^T @ SRC + rowbias, K=32 MFMA over chunk pairs
__device__ __forceinline__ void mmT(const unsigned short* __restrict__ w,
                                    const short4v (&src)[4][4],
                                    const float* __restrict__ bp,
                                    int g, int lane, float4v (&acc)[4][4]) {
  #pragma unroll
  for (int mt = 0; mt < 4; ++mt) {
    const float4v rb = rowbias(bp, mt, g);
    #pragma unroll
    for (int nt = 0; nt < 4; ++nt) acc[mt][nt] = rb;
  }
  #pragma unroll
  for (int k2 = 0; k2 < 2; ++k2) {
    short4v alo[4], ahi[4];
    #pragma unroll
    for (int mt = 0; mt < 4; ++mt) {
      alo[mt] = wsld(w, 2 * k2,     mt, lane);
      ahi[mt] = wsld(w, 2 * k2 + 1, mt, lane);
    }
    #pragma unroll
    for (int nt = 0; nt < 4; ++nt)
      #pragma unroll
      for (int mt = 0; mt < 4; ++mt)
        acc[mt][nt] = mfma32(alo[mt], ahi[mt],
                             src[2 * k2][nt], src[2 * k2 + 1][nt], acc[mt][nt]);
  }
}

// Pre-shuffle one 49x49 f32 matrix into padded 64x64 bf16 chunk-frag layout.
__global__ void __launch_bounds__(256)
prep_weights(const float* __restrict__ Wq, const float* __restrict__ Wk,
             const float* __restrict__ Wv, const float* __restrict__ Wh,
             const float* __restrict__ Wout, const float* __restrict__ W1,
             const float* __restrict__ W2, unsigned short* __restrict__ ws) {
  const int m = blockIdx.x;  // 0..167
  const float* src;
  if (m < 32)       src = Wq   + (size_t)m * D * D;
  else if (m < 64)  src = Wk   + (size_t)(m - 32) * D * D;
  else if (m < 96)  src = Wv   + (size_t)(m - 64) * D * D;
  else if (m < 128) src = Wh   + (size_t)(m - 96) * D * D;
  else if (m < 160) src = Wout + (size_t)(m - 128) * D * D;
  else if (m < 164) src = W1   + (size_t)(m - 160) * D * D;
  else              src = W2   + (size_t)(m - 164) * D * D;

  const int t = threadIdx.x;
  const int ktc = t >> 6, lane = t & 63;
  const int gg = lane >> 4, cc = lane & 15;
  #pragma unroll
  for (int nt = 0; nt < 4; ++nt) {
    short4v v;
    #pragma unroll
    for (int j = 0; j < 4; ++j) {
      const int k = 16 * ktc + 4 * gg + j;
      const int n = 16 * nt + cc;
      const float f = (k < D && n < D) ? src[k * D + n] : 0.0f;
      v[j] = (short)f2bf(f);
    }
    *reinterpret_cast<short4v*>(ws + (size_t)m * WSM + ((ktc * 4 + nt) * 64 + lane) * 4) = v;
  }
}

__global__ void __launch_bounds__(64, 2)
encoder_kernel(const float* __restrict__ emb, const int* __restrict__ labels,
               const unsigned short* __restrict__ ws,
               const float* __restrict__ bq, const float* __restrict__ bk,
               const float* __restrict__ bv, const float* __restrict__ bh,
               const float* __restrict__ b1, const float* __restrict__ b2,
               const float* __restrict__ Wc1, const float* __restrict__ bc1,
               const float* __restrict__ Wc2, const float* __restrict__ bc2,
               float* __restrict__ ws_loss, float* __restrict__ ws_corr) {
  __shared__ unsigned short X[64 * XS];  // residual stream, [row][col] bf16
  __shared__ float CLS[128];

  const int b = blockIdx.x;
  const int lane = threadIdx.x;          // one wave per block
  const int g = lane >> 4, c = lane & 15;

  // ---- X <- embedding (zero-padded to 64x64) ----
  for (int idx = lane; idx < 64 * 64; idx += 64) {
    const int r = idx >> 6, cc = idx & 63;
    const float v = (r < D && cc < D) ? emb[(size_t)b * (D * D) + r * D + cc] : 0.0f;
    X[r * XS + cc] = f2bf(v);
  }
  __syncthreads();

  const float invSCALE = 1.0f / (7.0f + 1e-6f);

  short4v xf[4][4];    // xf[ktc][mt]: X[16mt+c][16ktc+4g..+3] (A-chunk of X)
  float4v xacc[4][4];  // layer output cfrag (kept for pooling)

  #pragma unroll 1
  for (int l = 0; l < L; ++l) {
    #pragma unroll
    for (int ktc = 0; ktc < 4; ++ktc)
      #pragma unroll
      for (int mt = 0; mt < 4; ++mt)
        xf[ktc][mt] = *reinterpret_cast<const short4v*>(
            &X[(16 * mt + c) * XS + 16 * ktc + 4 * g]);

    float4v od[4][4];  // od^T f32 accumulator across heads
    #pragma unroll
    for (int mt = 0; mt < 4; ++mt)
      #pragma unroll
      for (int nt = 0; nt < 4; ++nt) od[mt][nt] = splat4(0.0f);

    #pragma unroll 1
    for (int h = 0; h < H; ++h) {
      const int lh = l * H + h;
      const unsigned short* wq = ws + (size_t)(0   + lh) * WSM;
      const unsigned short* wk = ws + (size_t)(32  + lh) * WSM;
      const unsigned short* wv = ws + (size_t)(64  + lh) * WSM;
      const unsigned short* wh = ws + (size_t)(96  + lh) * WSM;
      const unsigned short* wo = ws + (size_t)(128 + lh) * WSM;

      // ---- Q^T, K^T (cfrag; rows = e dim = next contraction chunk) ----
      float4v qa[4][4], ka[4][4];
      mmT(wq, xf, bq + lh * D, g, lane, qa);
      mmT(wk, xf, bk + lh * D, g, lane, ka);
      short4v qf[4][4], kf[4][4];
      #pragma unroll
      for (int mt = 0; mt < 4; ++mt)
        #pragma unroll
        for (int nt = 0; nt < 4; ++nt) { qf[mt][nt] = cvt4(qa[mt][nt]); kf[mt][nt] = cvt4(ka[mt][nt]); }

      // ---- S^T = K @ Q^T ----
      float4v s[4][4];
      #pragma unroll
      for (int mt = 0; mt < 4; ++mt)
        #pragma unroll
        for (int nt = 0; nt < 4; ++nt) s[mt][nt] = splat4(0.0f);
      #pragma unroll
      for (int k2 = 0; k2 < 2; ++k2)
        #pragma unroll
        for (int nt = 0; nt < 4; ++nt)
          #pragma unroll
          for (int mt = 0; mt < 4; ++mt)
            s[mt][nt] = mfma32(kf[2 * k2][mt], kf[2 * k2 + 1][mt],
                               qf[2 * k2][nt], qf[2 * k2 + 1][nt], s[mt][nt]);

      // ---- scale, clip, mask pad keys j=16mt+4g+r>=49, softmax over j ----
      #pragma unroll
      for (int mt = 0; mt < 4; ++mt)
        #pragma unroll
        for (int nt = 0; nt < 4; ++nt)
          #pragma unroll
          for (int r = 0; r < 4; ++r) {
            float sv = s[mt][nt][r] * invSCALE;
            sv = fminf(fmaxf(sv, -30.0f), 30.0f);
            if (mt == 3) sv = (r == 0 && g == 0) ? sv : NEGBIG;
            s[mt][nt][r] = sv;
          }
      float inv_[4];
      #pragma unroll
      for (int nt = 0; nt < 4; ++nt) {
        float mx = s[0][nt][0];
        #pragma unroll
        for (int mt = 0; mt < 4; ++mt)
          #pragma unroll
          for (int r = 0; r < 4; ++r) mx = fmaxf(mx, s[mt][nt][r]);
        mx = fmaxf(mx, __shfl_xor(mx, 16));
        mx = fmaxf(mx, __shfl_xor(mx, 32));
        float dn = 0.0f;
        #pragma unroll
        for (int mt = 0; mt < 4; ++mt)
          #pragma unroll
          for (int r = 0; r < 4; ++r) {
            const float p = __expf(s[mt][nt][r] - mx);
            s[mt][nt][r] = p;
            dn += p;
          }
        dn += __shfl_xor(dn, 16);
        dn += __shfl_xor(dn, 32);
        inv_[nt] = 1.0f / fmaxf(dn, 1e-37f);
      }
      short4v pf[4][4];
      #pragma unroll
      for (int mt = 0; mt < 4; ++mt)
        #pragma unroll
        for (int nt = 0; nt < 4; ++nt) pf[mt][nt] = cvt4(s[mt][nt]);

      // ---- V = X @ Wv + bv (cfrag(V); rows = patch, cols = e) ----
      float4v va[4][4];
      #pragma unroll
      for (int nt = 0; nt < 4; ++nt) {
        const int e = 16 * nt + c;
        const float bvv = (e < D) ? bv[lh * D + e] : 0.0f;
        #pragma unroll
        for (int mt = 0; mt < 4; ++mt) va[mt][nt] = splat4(bvv);
      }
      #pragma unroll
      for (int k2 = 0; k2 < 2; ++k2) {
        short4v blo[4], bhi[4];
        #pragma unroll
        for (int nt = 0; nt < 4; ++nt) {
          blo[nt] = wsld(wv, 2 * k2,     nt, lane);
          bhi[nt] = wsld(wv, 2 * k2 + 1, nt, lane);
        }
        #pragma unroll
        for (int nt = 0; nt < 4; ++nt)
          #pragma unroll
          for (int mt = 0; mt < 4; ++mt)
            va[mt][nt] = mfma32(xf[2 * k2][mt], xf[2 * k2 + 1][mt],
                                blo[nt], bhi[nt], va[mt][nt]);
      }
      short4v vf[4][4];
      #pragma unroll
      for (int mt = 0; mt < 4; ++mt)
        #pragma unroll
        for (int nt = 0; nt < 4; ++nt) vf[mt][nt] = cvt4(va[mt][nt]);

      // ---- ctx^T = V^T @ P^T, then * inv_den per column ----
      float4v ca[4][4];
      #pragma unroll
      for (int mt = 0; mt < 4; ++mt)
        #pragma unroll
        for (int nt = 0; nt < 4; ++nt) ca[mt][nt] = splat4(0.0f);
      #pragma unroll
      for (int k2 = 0; k2 < 2; ++k2)
        #pragma unroll
        for (int nt = 0; nt < 4; ++nt)
          #pragma unroll
          for (int mt = 0; mt < 4; ++mt)
            ca[mt][nt] = mfma32(vf[2 * k2][mt], vf[2 * k2 + 1][mt],
                                pf[2 * k2][nt], pf[2 * k2 + 1][nt], ca[mt][nt]);
      short4v cf[4][4];
      #pragma unroll
      for (int mt = 0; mt < 4; ++mt)
        #pragma unroll
        for (int nt = 0; nt < 4; ++nt) cf[mt][nt] = cvt4(ca[mt][nt] * inv_[nt]);

      // ---- ho^T = Wh^T @ ctx^T + bh ----
      float4v ha[4][4];
      mmT(wh, cf, bh + lh * D, g, lane, ha);
      short4v hf[4][4];
      #pragma unroll
      for (int mt = 0; mt < 4; ++mt)
        #pragma unroll
        for (int nt = 0; nt < 4; ++nt) hf[mt][nt] = cvt4(ha[mt][nt]);

      // ---- od^T += Wout^T @ ho^T ----
      #pragma unroll
      for (int k2 = 0; k2 < 2; ++k2) {
        short4v alo[4], ahi[4];
        #pragma unroll
        for (int mt = 0; mt < 4; ++mt) {
          alo[mt] = wsld(wo, 2 * k2,     mt, lane);
          ahi[mt] = wsld(wo, 2 * k2 + 1, mt, lane);
        }
        #pragma unroll
        for (int nt = 0; nt < 4; ++nt)
          #pragma unroll
          for (int mt = 0; mt < 4; ++mt)
            od[mt][nt] = mfma32(alo[mt], ahi[mt],
                                hf[2 * k2][nt], hf[2 * k2 + 1][nt], od[mt][nt]);
      }
    }  // heads

    // ---- MLP: t^T = W1^T @ od^T + b1; x_new = t @ W2 + b2 ----
    short4v of[4][4];
    #pragma unroll
    for (int mt = 0; mt < 4; ++mt)
      #pragma unroll
      for (int nt = 0; nt < 4; ++nt) of[mt][nt] = cvt4(od[mt][nt]);
    float4v ta[4][4];
    mmT(ws + (size_t)(160 + l) * WSM, of, b1 + l * D, g, lane, ta);
    short4v tf[4][4];
    #pragma unroll
    for (int mt = 0; mt < 4; ++mt)
      #pragma unroll
      for (int nt = 0; nt < 4; ++nt) tf[mt][nt] = cvt4(ta[mt][nt]);

    const unsigned short* w2p = ws + (size_t)(164 + l) * WSM;
    #pragma unroll
    for (int nt = 0; nt < 4; ++nt) {
      const int e = 16 * nt + c;
      const float bvv = (e < D) ? b2[l * D + e] : 0.0f;
      #pragma unroll
      for (int mt = 0; mt < 4; ++mt) xacc[mt][nt] = splat4(bvv);
    }
    #pragma unroll
    for (int k2 = 0; k2 < 2; ++k2) {
      short4v blo[4], bhi[4];
      #pragma unroll
      for (int nt = 0; nt < 4; ++nt) {
        blo[nt] = wsld(w2p, 2 * k2,     nt, lane);
        bhi[nt] = wsld(w2p, 2 * k2 + 1, nt, lane);
      }
      #pragma unroll
      for (int nt = 0; nt < 4; ++nt)
        #pragma unroll
        for (int mt = 0; mt < 4; ++mt)
          xacc[mt][nt] = mfma32(tf[2 * k2][mt], tf[2 * k2 + 1][mt],
                                blo[nt], bhi[nt], xacc[mt][nt]);
    }

    if (l < L - 1) {
      __syncthreads();
      #pragma unroll
      for (int mt = 0; mt < 4; ++mt)
        #pragma unroll
        for (int nt = 0; nt < 4; ++nt)
          #pragma unroll
          for (int r = 0; r < 4; ++r)
            X[(16 * mt + 4 * g + r) * XS + 16 * nt + c] = f2bf(xacc[mt][nt][r]);
      __syncthreads();
    }
  }  // layers

  // ---- pooled = mean over rows<49 ----
  float ps[4];
  #pragma unroll
  for (int nt = 0; nt < 4; ++nt) {
    float sum = 0.0f;
    #pragma unroll
    for (int mt = 0; mt < 3; ++mt)
      #pragma unroll
      for (int r = 0; r < 4; ++r) sum += xacc[mt][nt][r];
    if (g == 0) sum += xacc[3][nt][0];  // row 48
    sum += __shfl_xor(sum, 16);
    sum += __shfl_xor(sum, 32);
    ps[nt] = sum * (1.0f / 49.0f);
  }
  if (lane < 16) {
    #pragma unroll
    for (int nt = 0; nt < 4; ++nt) CLS[16 * nt + lane] = ps[nt];
  }
  __syncthreads();

  if (lane < HID) {
    float acc = bc1[lane];
    #pragma unroll 1
    for (int d = 0; d < D; ++d) acc = fmaf(CLS[d], Wc1[d * HID + lane], acc);
    CLS[64 + lane] = acc;
  }
  __syncthreads();
  if (lane < NCLS) {
    float acc = bc2[lane];
    #pragma unroll 1
    for (int j = 0; j < HID; ++j) acc = fmaf(CLS[64 + j], Wc2[j * NCLS + lane], acc);
    CLS[96 + lane] = acc;
  }
  __syncthreads();
  if (lane == 0) {
    float mx = CLS[96];
    int am = 0;
    #pragma unroll 1
    for (int cc = 1; cc < NCLS; ++cc) {
      const float v = CLS[96 + cc];
      if (v > mx) { mx = v; am = cc; }  // strict '>' == first max (jnp.argmax)
    }
    float se = 0.0f;
    #pragma unroll 1
    for (int cc = 0; cc < NCLS; ++cc) se += expf(CLS[96 + cc] - mx);
    const float lse = mx + logf(se);
    const int lbl = labels[b];
    ws_loss[b] = lse - CLS[96 + lbl];
    ws_corr[b] = (am == lbl) ? 1.0f : 0.0f;
  }
}

__global__ void __launch_bounds__(256)
reduce_kernel(const float* __restrict__ wsl, const float* __restrict__ wsc,
              float* __restrict__ out, int n) {
  __shared__ float sl[256];
  __shared__ float sc[256];
  const int t = threadIdx.x;
  float a = 0.0f, cc = 0.0f;
  for (int idx = t; idx < n; idx += 256) { a += wsl[idx]; cc += wsc[idx]; }
  sl[t] = a; sc[t] = cc;
  __syncthreads();
  for (int s = 128; s > 0; s >>= 1) {
    if (t < s) { sl[t] += sl[t + s]; sc[t] += sc[t + s]; }
    __syncthreads();
  }
  if (t == 0) {
    out[0] = sl[0] / (float)n;
    out[1] = sc[0] / (float)n;
  }
}

}  // namespace

extern "C" void kernel_launch(void* const* d_in, const int* in_sizes, int n_in,
                              void* d_out, int out_size, void* d_ws, size_t ws_size,
                              hipStream_t stream) {
  const float* emb    = (const float*)d_in[0];
  const int*   labels = (const int*)d_in[1];
  const float* Wq   = (const float*)d_in[2];
  const float* bq   = (const float*)d_in[3];
  const float* Wk   = (const float*)d_in[4];
  const float* bk   = (const float*)d_in[5];
  const float* Wv   = (const float*)d_in[6];
  const float* bv   = (const float*)d_in[7];
  const float* Wh   = (const float*)d_in[8];
  const float* bh   = (const float*)d_in[9];
  const float* Wout = (const float*)d_in[10];
  const float* W1   = (const float*)d_in[11];
  const float* b1   = (const float*)d_in[12];
  const float* W2   = (const float*)d_in[13];
  const float* b2   = (const float*)d_in[14];
  const float* Wc1  = (const float*)d_in[15];
  const float* bc1  = (const float*)d_in[16];
  const float* Wc2  = (const float*)d_in[17];
  const float* bc2  = (const float*)d_in[18];

  const int B = in_sizes[1];  // 2048
  const size_t wBytes = (size_t)168 * WSM * sizeof(unsigned short);
  const size_t need = wBytes + (size_t)2 * B * sizeof(float);
  if (ws_size < need) return;

  unsigned short* wsb = (unsigned short*)d_ws;
  float* wsf = (float*)((char*)d_ws + wBytes);
  float* out = (float*)d_out;

  prep_weights<<<168, 256, 0, stream>>>(Wq, Wk, Wv, Wh, Wout, W1, W2, wsb);
  encoder_kernel<<<B, 64, 0, stream>>>(emb, labels, wsb, bq, bk, bv, bh,
                                       b1, b2, Wc1, bc1, Wc2, bc2,
                                       wsf, wsf + B);
  reduce_kernel<<<1, 256, 0, stream>>>(wsf, wsf + B, out, B);
}

// Round 6
// 364.616 us; speedup vs baseline: 13.1508x; 1.0052x over previous
//
#include <hip/hip_runtime.h>
#include <math.h>

namespace {

constexpr int D    = 49;
constexpr int H    = 8;
constexpr int L    = 4;
constexpr int HID  = 25;
constexpr int NCLS = 10;
constexpr int XS   = 68;    // LDS X row stride (bf16 elems)
constexpr int WSM  = 4096;  // ushorts per padded 64x64 matrix in chunk-frag layout
constexpr float NEGBIG = -1e30f;  // finite mask: exp(NEGBIG - mx) == 0, no inf-inf

typedef __attribute__((ext_vector_type(4))) short short4v;
typedef __attribute__((ext_vector_type(8))) short short8v;
typedef __attribute__((ext_vector_type(4))) float float4v;
typedef __attribute__((ext_vector_type(4))) __bf16 bf16x4;

// One 16x16x32 bf16 MFMA; operands = concat of two 4-elem k-chunks.
// Consistent A/B chunk packing => correct contraction regardless of HW k-map.
__device__ __forceinline__ float4v mfma32(short4v alo, short4v ahi,
                                          short4v blo, short4v bhi, float4v c) {
  short8v a = __builtin_shufflevector(alo, ahi, 0, 1, 2, 3, 4, 5, 6, 7);
  short8v b = __builtin_shufflevector(blo, bhi, 0, 1, 2, 3, 4, 5, 6, 7);
  return __builtin_amdgcn_mfma_f32_16x16x32_bf16(a, b, c, 0, 0, 0);
}

__device__ __forceinline__ unsigned short f2bf(float x) {  // RNE bit-twiddle
  unsigned u = __float_as_uint(x);
  return (unsigned short)((u + 0x7FFFu + ((u >> 16) & 1u)) >> 16);
}

__device__ __forceinline__ short4v cvt4(float4v v) {  // 4xf32 -> 4xbf16 (compiler cvt)
  bf16x4 b = {(__bf16)v[0], (__bf16)v[1], (__bf16)v[2], (__bf16)v[3]};
  return __builtin_bit_cast(short4v, b);
}

__device__ __forceinline__ float4v splat4(float x) {
  float4v v; v[0] = x; v[1] = x; v[2] = x; v[3] = x; return v;
}

// chunk-frag (ktc, nt) of a prepped 64x64 matrix: semantic k = 16*ktc+4*g+j, col = 16*nt+c
__device__ __forceinline__ short4v wsld(const unsigned short* __restrict__ w,
                                        int ktc, int nt, int lane) {
  return *reinterpret_cast<const short4v*>(w + ((ktc * 4 + nt) * 64 + lane) * 4);
}

__device__ __forceinline__ float4v rowbias(const float* __restrict__ bp, int mt, int g) {
  float4v r;
  #pragma unroll
  for (int i = 0; i < 4; ++i) {
    const int e = 16 * mt + 4 * g + i;
    r[i] = (e < D) ? bp[e] : 0.0f;
  }
  return r;
}

// acc(cfrag of OUT^T) = W^T @ SRC + rowbias, K=32 MFMA over chunk pairs
__device__ __forceinline__ void mmT(const unsigned short* __restrict__ w,
                                    const short4v (&src)[4][4],
                                    const float* __restrict__ bp,
                                    int g, int lane, float4v (&acc)[4][4]) {
  #pragma unroll
  for (int mt = 0; mt < 4; ++mt) {
    const float4v rb = rowbias(bp, mt, g);
    #pragma unroll
    for (int nt = 0; nt < 4; ++nt) acc[mt][nt] = rb;
  }
  #pragma unroll
  for (int k2 = 0; k2 < 2; ++k2) {
    short4v alo[4], ahi[4];
    #pragma unroll
    for (int mt = 0; mt < 4; ++mt) {
      alo[mt] = wsld(w, 2 * k2,     mt, lane);
      ahi[mt] = wsld(w, 2 * k2 + 1, mt, lane);
    }
    #pragma unroll
    for (int nt = 0; nt < 4; ++nt)
      #pragma unroll
      for (int mt = 0; mt < 4; ++mt)
        acc[mt][nt] = mfma32(alo[mt], ahi[mt],
                             src[2 * k2][nt], src[2 * k2 + 1][nt], acc[mt][nt]);
  }
}

// Pre-shuffle one 49x49 f32 matrix into padded 64x64 bf16 chunk-frag layout.
__global__ void __launch_bounds__(256)
prep_weights(const float* __restrict__ Wq, const float* __restrict__ Wk,
             const float* __restrict__ Wv, const float* __restrict__ Wh,
             const float* __restrict__ Wout, const float* __restrict__ W1,
             const float* __restrict__ W2, unsigned short* __restrict__ ws) {
  const int m = blockIdx.x;  // 0..167
  const float* src;
  if (m < 32)       src = Wq   + (size_t)m * D * D;
  else if (m < 64)  src = Wk   + (size_t)(m - 32) * D * D;
  else if (m < 96)  src = Wv   + (size_t)(m - 64) * D * D;
  else if (m < 128) src = Wh   + (size_t)(m - 96) * D * D;
  else if (m < 160) src = Wout + (size_t)(m - 128) * D * D;
  else if (m < 164) src = W1   + (size_t)(m - 160) * D * D;
  else              src = W2   + (size_t)(m - 164) * D * D;

  const int t = threadIdx.x;
  const int ktc = t >> 6, lane = t & 63;
  const int gg = lane >> 4, cc = lane & 15;
  #pragma unroll
  for (int nt = 0; nt < 4; ++nt) {
    short4v v;
    #pragma unroll
    for (int j = 0; j < 4; ++j) {
      const int k = 16 * ktc + 4 * gg + j;
      const int n = 16 * nt + cc;
      const float f = (k < D && n < D) ? src[k * D + n] : 0.0f;
      v[j] = (short)f2bf(f);
    }
    *reinterpret_cast<short4v*>(ws + (size_t)m * WSM + ((ktc * 4 + nt) * 64 + lane) * 4) = v;
  }
}

__global__ void __launch_bounds__(64, 2)
encoder_kernel(const float* __restrict__ emb, const int* __restrict__ labels,
               const unsigned short* __restrict__ ws,
               const float* __restrict__ bq, const float* __restrict__ bk,
               const float* __restrict__ bv, const float* __restrict__ bh,
               const float* __restrict__ b1, const float* __restrict__ b2,
               const float* __restrict__ Wc1, const float* __restrict__ bc1,
               const float* __restrict__ Wc2, const float* __restrict__ bc2,
               float* __restrict__ ws_loss, float* __restrict__ ws_corr) {
  __shared__ unsigned short X[64 * XS];  // residual stream, [row][col] bf16
  __shared__ float CLS[128];

  const int b = blockIdx.x;
  const int lane = threadIdx.x;          // one wave per block
  const int g = lane >> 4, c = lane & 15;

  // ---- X <- embedding (zero-padded to 64x64) ----
  for (int idx = lane; idx < 64 * 64; idx += 64) {
    const int r = idx >> 6, cc = idx & 63;
    const float v = (r < D && cc < D) ? emb[(size_t)b * (D * D) + r * D + cc] : 0.0f;
    X[r * XS + cc] = f2bf(v);
  }
  __syncthreads();

  const float invSCALE = 1.0f / (7.0f + 1e-6f);

  short4v xf[4][4];    // xf[ktc][mt]: X[16mt+c][16ktc+4g..+3] (A-chunk of X)
  float4v xacc[4][4];  // layer output cfrag (kept for pooling)

  #pragma unroll 1
  for (int l = 0; l < L; ++l) {
    #pragma unroll
    for (int ktc = 0; ktc < 4; ++ktc)
      #pragma unroll
      for (int mt = 0; mt < 4; ++mt)
        xf[ktc][mt] = *reinterpret_cast<const short4v*>(
            &X[(16 * mt + c) * XS + 16 * ktc + 4 * g]);

    float4v od[4][4];  // od^T f32 accumulator across heads
    #pragma unroll
    for (int mt = 0; mt < 4; ++mt)
      #pragma unroll
      for (int nt = 0; nt < 4; ++nt) od[mt][nt] = splat4(0.0f);

    #pragma unroll 1
    for (int h = 0; h < H; ++h) {
      const int lh = l * H + h;
      const unsigned short* wq = ws + (size_t)(0   + lh) * WSM;
      const unsigned short* wk = ws + (size_t)(32  + lh) * WSM;
      const unsigned short* wv = ws + (size_t)(64  + lh) * WSM;
      const unsigned short* wh = ws + (size_t)(96  + lh) * WSM;
      const unsigned short* wo = ws + (size_t)(128 + lh) * WSM;

      // ---- Q^T, K^T (cfrag; rows = e dim = next contraction chunk) ----
      float4v qa[4][4], ka[4][4];
      mmT(wq, xf, bq + lh * D, g, lane, qa);
      mmT(wk, xf, bk + lh * D, g, lane, ka);
      short4v qf[4][4], kf[4][4];
      #pragma unroll
      for (int mt = 0; mt < 4; ++mt)
        #pragma unroll
        for (int nt = 0; nt < 4; ++nt) { qf[mt][nt] = cvt4(qa[mt][nt]); kf[mt][nt] = cvt4(ka[mt][nt]); }

      // ---- S^T = K @ Q^T ----
      float4v s[4][4];
      #pragma unroll
      for (int mt = 0; mt < 4; ++mt)
        #pragma unroll
        for (int nt = 0; nt < 4; ++nt) s[mt][nt] = splat4(0.0f);
      #pragma unroll
      for (int k2 = 0; k2 < 2; ++k2)
        #pragma unroll
        for (int nt = 0; nt < 4; ++nt)
          #pragma unroll
          for (int mt = 0; mt < 4; ++mt)
            s[mt][nt] = mfma32(kf[2 * k2][mt], kf[2 * k2 + 1][mt],
                               qf[2 * k2][nt], qf[2 * k2 + 1][nt], s[mt][nt]);

      // ---- scale, clip, mask pad keys j=16mt+4g+r>=49, softmax over j ----
      #pragma unroll
      for (int mt = 0; mt < 4; ++mt)
        #pragma unroll
        for (int nt = 0; nt < 4; ++nt)
          #pragma unroll
          for (int r = 0; r < 4; ++r) {
            float sv = s[mt][nt][r] * invSCALE;
            sv = fminf(fmaxf(sv, -30.0f), 30.0f);
            if (mt == 3) sv = (r == 0 && g == 0) ? sv : NEGBIG;
            s[mt][nt][r] = sv;
          }
      float inv_[4];
      #pragma unroll
      for (int nt = 0; nt < 4; ++nt) {
        float mx = s[0][nt][0];
        #pragma unroll
        for (int mt = 0; mt < 4; ++mt)
          #pragma unroll
          for (int r = 0; r < 4; ++r) mx = fmaxf(mx, s[mt][nt][r]);
        mx = fmaxf(mx, __shfl_xor(mx, 16));
        mx = fmaxf(mx, __shfl_xor(mx, 32));
        float dn = 0.0f;
        #pragma unroll
        for (int mt = 0; mt < 4; ++mt)
          #pragma unroll
          for (int r = 0; r < 4; ++r) {
            const float p = __expf(s[mt][nt][r] - mx);
            s[mt][nt][r] = p;
            dn += p;
          }
        dn += __shfl_xor(dn, 16);
        dn += __shfl_xor(dn, 32);
        inv_[nt] = 1.0f / fmaxf(dn, 1e-37f);
      }
      short4v pf[4][4];
      #pragma unroll
      for (int mt = 0; mt < 4; ++mt)
        #pragma unroll
        for (int nt = 0; nt < 4; ++nt) pf[mt][nt] = cvt4(s[mt][nt]);

      // ---- V = X @ Wv + bv (cfrag(V); rows = patch, cols = e) ----
      float4v va[4][4];
      #pragma unroll
      for (int nt = 0; nt < 4; ++nt) {
        const int e = 16 * nt + c;
        const float bvv = (e < D) ? bv[lh * D + e] : 0.0f;
        #pragma unroll
        for (int mt = 0; mt < 4; ++mt) va[mt][nt] = splat4(bvv);
      }
      #pragma unroll
      for (int k2 = 0; k2 < 2; ++k2) {
        short4v blo[4], bhi[4];
        #pragma unroll
        for (int nt = 0; nt < 4; ++nt) {
          blo[nt] = wsld(wv, 2 * k2,     nt, lane);
          bhi[nt] = wsld(wv, 2 * k2 + 1, nt, lane);
        }
        #pragma unroll
        for (int nt = 0; nt < 4; ++nt)
          #pragma unroll
          for (int mt = 0; mt < 4; ++mt)
            va[mt][nt] = mfma32(xf[2 * k2][mt], xf[2 * k2 + 1][mt],
                                blo[nt], bhi[nt], va[mt][nt]);
      }
      short4v vf[4][4];
      #pragma unroll
      for (int mt = 0; mt < 4; ++mt)
        #pragma unroll
        for (int nt = 0; nt < 4; ++nt) vf[mt][nt] = cvt4(va[mt][nt]);

      // ---- ctx^T = V^T @ P^T, then * inv_den per column ----
      float4v ca[4][4];
      #pragma unroll
      for (int mt = 0; mt < 4; ++mt)
        #pragma unroll
        for (int nt = 0; nt < 4; ++nt) ca[mt][nt] = splat4(0.0f);
      #pragma unroll
      for (int k2 = 0; k2 < 2; ++k2)
        #pragma unroll
        for (int nt = 0; nt < 4; ++nt)
          #pragma unroll
          for (int mt = 0; mt < 4; ++mt)
            ca[mt][nt] = mfma32(vf[2 * k2][mt], vf[2 * k2 + 1][mt],
                                pf[2 * k2][nt], pf[2 * k2 + 1][nt], ca[mt][nt]);
      short4v cf[4][4];
      #pragma unroll
      for (int mt = 0; mt < 4; ++mt)
        #pragma unroll
        for (int nt = 0; nt < 4; ++nt) cf[mt][nt] = cvt4(ca[mt][nt] * inv_[nt]);

      // ---- ho^T = Wh^T @ ctx^T + bh ----
      float4v ha[4][4];
      mmT(wh, cf, bh + lh * D, g, lane, ha);
      short4v hf[4][4];
      #pragma unroll
      for (int mt = 0; mt < 4; ++mt)
        #pragma unroll
        for (int nt = 0; nt < 4; ++nt) hf[mt][nt] = cvt4(ha[mt][nt]);

      // ---- od^T += Wout^T @ ho^T ----
      #pragma unroll
      for (int k2 = 0; k2 < 2; ++k2) {
        short4v alo[4], ahi[4];
        #pragma unroll
        for (int mt = 0; mt < 4; ++mt) {
          alo[mt] = wsld(wo, 2 * k2,     mt, lane);
          ahi[mt] = wsld(wo, 2 * k2 + 1, mt, lane);
        }
        #pragma unroll
        for (int nt = 0; nt < 4; ++nt)
          #pragma unroll
          for (int mt = 0; mt < 4; ++mt)
            od[mt][nt] = mfma32(alo[mt], ahi[mt],
                                hf[2 * k2][nt], hf[2 * k2 + 1][nt], od[mt][nt]);
      }
    }  // heads

    // ---- MLP: t^T = W1^T @ od^T + b1; x_new = t @ W2 + b2 ----
    short4v of[4][4];
    #pragma unroll
    for (int mt = 0; mt < 4; ++mt)
      #pragma unroll
      for (int nt = 0; nt < 4; ++nt) of[mt][nt] = cvt4(od[mt][nt]);
    float4v ta[4][4];
    mmT(ws + (size_t)(160 + l) * WSM, of, b1 + l * D, g, lane, ta);
    short4v tf[4][4];
    #pragma unroll
    for (int mt = 0; mt < 4; ++mt)
      #pragma unroll
      for (int nt = 0; nt < 4; ++nt) tf[mt][nt] = cvt4(ta[mt][nt]);

    const unsigned short* w2p = ws + (size_t)(164 + l) * WSM;
    #pragma unroll
    for (int nt = 0; nt < 4; ++nt) {
      const int e = 16 * nt + c;
      const float bvv = (e < D) ? b2[l * D + e] : 0.0f;
      #pragma unroll
      for (int mt = 0; mt < 4; ++mt) xacc[mt][nt] = splat4(bvv);
    }
    #pragma unroll
    for (int k2 = 0; k2 < 2; ++k2) {
      short4v blo[4], bhi[4];
      #pragma unroll
      for (int nt = 0; nt < 4; ++nt) {
        blo[nt] = wsld(w2p, 2 * k2,     nt, lane);
        bhi[nt] = wsld(w2p, 2 * k2 + 1, nt, lane);
      }
      #pragma unroll
      for (int nt = 0; nt < 4; ++nt)
        #pragma unroll
        for (int mt = 0; mt < 4; ++mt)
          xacc[mt][nt] = mfma32(tf[2 * k2][mt], tf[2 * k2 + 1][mt],
                                blo[nt], bhi[nt], xacc[mt][nt]);
    }

    if (l < L - 1) {
      __syncthreads();
      #pragma unroll
      for (int mt = 0; mt < 4; ++mt)
        #pragma unroll
        for (int nt = 0; nt < 4; ++nt)
          #pragma unroll
          for (int r = 0; r < 4; ++r)
            X[(16 * mt + 4 * g + r) * XS + 16 * nt + c] = f2bf(xacc[mt][nt][r]);
      __syncthreads();
    }
  }  // layers

  // ---- pooled = mean over rows<49 ----
  float ps[4];
  #pragma unroll
  for (int nt = 0; nt < 4; ++nt) {
    float sum = 0.0f;
    #pragma unroll
    for (int mt = 0; mt < 3; ++mt)
      #pragma unroll
      for (int r = 0; r < 4; ++r) sum += xacc[mt][nt][r];
    if (g == 0) sum += xacc[3][nt][0];  // row 48
    sum += __shfl_xor(sum, 16);
    sum += __shfl_xor(sum, 32);
    ps[nt] = sum * (1.0f / 49.0f);
  }
  if (lane < 16) {
    #pragma unroll
    for (int nt = 0; nt < 4; ++nt) CLS[16 * nt + lane] = ps[nt];
  }
  __syncthreads();

  if (lane < HID) {
    float acc = bc1[lane];
    #pragma unroll 1
    for (int d = 0; d < D; ++d) acc = fmaf(CLS[d], Wc1[d * HID + lane], acc);
    CLS[64 + lane] = acc;
  }
  __syncthreads();
  if (lane < NCLS) {
    float acc = bc2[lane];
    #pragma unroll 1
    for (int j = 0; j < HID; ++j) acc = fmaf(CLS[64 + j], Wc2[j * NCLS + lane], acc);
    CLS[96 + lane] = acc;
  }
  __syncthreads();
  if (lane == 0) {
    float mx = CLS[96];
    int am = 0;
    #pragma unroll 1
    for (int cc = 1; cc < NCLS; ++cc) {
      const float v = CLS[96 + cc];
      if (v > mx) { mx = v; am = cc; }  // strict '>' == first max (jnp.argmax)
    }
    float se = 0.0f;
    #pragma unroll 1
    for (int cc = 0; cc < NCLS; ++cc) se += expf(CLS[96 + cc] - mx);
    const float lse = mx + logf(se);
    const int lbl = labels[b];
    ws_loss[b] = lse - CLS[96 + lbl];
    ws_corr[b] = (am == lbl) ? 1.0f : 0.0f;
  }
}

__global__ void __launch_bounds__(256)
reduce_kernel(const float* __restrict__ wsl, const float* __restrict__ wsc,
              float* __restrict__ out, int n) {
  __shared__ float sl[256];
  __shared__ float sc[256];
  const int t = threadIdx.x;
  float a = 0.0f, cc = 0.0f;
  for (int idx = t; idx < n; idx += 256) { a += wsl[idx]; cc += wsc[idx]; }
  sl[t] = a; sc[t] = cc;
  __syncthreads();
  for (int s = 128; s > 0; s >>= 1) {
    if (t < s) { sl[t] += sl[t + s]; sc[t] += sc[t + s]; }
    __syncthreads();
  }
  if (t == 0) {
    out[0] = sl[0] / (float)n;
    out[1] = sc[0] / (float)n;
  }
}

}  // namespace

extern "C" void kernel_launch(void* const* d_in, const int* in_sizes, int n_in,
                              void* d_out, int out_size, void* d_ws, size_t ws_size,
                              hipStream_t stream) {
  const float* emb    = (const float*)d_in[0];
  const int*   labels = (const int*)d_in[1];
  const float* Wq   = (const float*)d_in[2];
  const float* bq   = (const float*)d_in[3];
  const float* Wk   = (const float*)d_in[4];
  const float* bk   = (const float*)d_in[5];
  const float* Wv   = (const float*)d_in[6];
  const float* bv   = (const float*)d_in[7];
  const float* Wh   = (const float*)d_in[8];
  const float* bh   = (const float*)d_in[9];
  const float* Wout = (const float*)d_in[10];
  const float* W1   = (const float*)d_in[11];
  const float* b1   = (const float*)d_in[12];
  const float* W2   = (const float*)d_in[13];
  const float* b2   = (const float*)d_in[14];
  const float* Wc1  = (const float*)d_in[15];
  const float* bc1  = (const float*)d_in[16];
  const float* Wc2  = (const float*)d_in[17];
  const float* bc2  = (const float*)d_in[18];

  const int B = in_sizes[1];  // 2048
  const size_t wBytes = (size_t)168 * WSM * sizeof(unsigned short);
  const size_t need = wBytes + (size_t)2 * B * sizeof(float);
  if (ws_size < need) return;

  unsigned short* wsb = (unsigned short*)d_ws;
  float* wsf = (float*)((char*)d_ws + wBytes);
  float* out = (float*)d_out;

  prep_weights<<<168, 256, 0, stream>>>(Wq, Wk, Wv, Wh, Wout, W1, W2, wsb);
  encoder_kernel<<<B, 64, 0, stream>>>(emb, labels, wsb, bq, bk, bv, bh,
                                       b1, b2, Wc1, bc1, Wc2, bc2,
                                       wsf, wsf + B);
  reduce_kernel<<<1, 256, 0, stream>>>(wsf, wsf + B, out, B);
}